// Round 1
// baseline (883.892 us; speedup 1.0000x reference)
//
#include <hip/hip_runtime.h>
#include <hip/hip_bf16.h>

#define NN 100000     // nodes
#define NE 1600000    // edges
#define NGR 512       // graphs
#define KF 128        // IN_F == H1 == K of both GEMMs
#define H2F 256
#define NGRP 16
#define NFAM 10

#define SCAN_CHUNK 1024
#define SCAN_NB ((NN + SCAN_CHUNK - 1) / SCAN_CHUNK)

typedef __hip_bfloat16 bf16;
typedef __hip_bfloat162 bf162;

__device__ __forceinline__ float toF(float v) { return v; }
__device__ __forceinline__ float toF(bf16 v) { return __bfloat162float(v); }

// ---------------- CSR build ----------------

__global__ void k_hist(const int* __restrict__ ei, int* __restrict__ cnt) {
  int e = blockIdx.x * blockDim.x + threadIdx.x;
  if (e < NE) atomicAdd(&cnt[ei[NE + e]], 1);
}

__global__ void k_scan1(const int* __restrict__ cnt, int* __restrict__ bsum) {
  __shared__ int sh[256];
  int base = blockIdx.x * SCAN_CHUNK;
  int t = threadIdx.x;
  int s = 0;
  for (int i = t; i < SCAN_CHUNK; i += 256) {
    int idx = base + i;
    s += (idx < NN) ? cnt[idx] : 0;
  }
  sh[t] = s;
  __syncthreads();
  for (int off = 128; off > 0; off >>= 1) {
    if (t < off) sh[t] += sh[t + off];
    __syncthreads();
  }
  if (t == 0) bsum[blockIdx.x] = sh[0];
}

__global__ void k_scan2(const int* __restrict__ bsum, int* __restrict__ boff) {
  if (threadIdx.x == 0) {
    int acc = 0;
    for (int b = 0; b < SCAN_NB; ++b) { boff[b] = acc; acc += bsum[b]; }
  }
}

__global__ void k_scan3(const int* __restrict__ cnt, const int* __restrict__ boff,
                        int* __restrict__ rowptr) {
  __shared__ int sh[256];
  int base = blockIdx.x * SCAN_CHUNK;
  int t = threadIdx.x;
  int i0 = base + t * 4;
  int v[4];
  int loc = 0;
#pragma unroll
  for (int j = 0; j < 4; ++j) {
    int idx = i0 + j;
    v[j] = (idx < NN) ? cnt[idx] : 0;
    loc += v[j];
  }
  sh[t] = loc;
  __syncthreads();
  for (int off = 1; off < 256; off <<= 1) {
    int val = (t >= off) ? sh[t - off] : 0;
    __syncthreads();
    sh[t] += val;
    __syncthreads();
  }
  int excl = sh[t] - loc + boff[blockIdx.x];
#pragma unroll
  for (int j = 0; j < 4; ++j) {
    int idx = i0 + j;
    if (idx < NN) rowptr[idx] = excl;
    excl += v[j];
  }
  if (blockIdx.x == 0 && t == 0) rowptr[NN] = NE;
}

__global__ void k_dinv(const int* __restrict__ rowptr, float* __restrict__ dinv,
                       int* __restrict__ fillpos) {
  int i = blockIdx.x * blockDim.x + threadIdx.x;
  if (i < NN) {
    int r0 = rowptr[i];
    int deg = rowptr[i + 1] - r0 + 1;  // +1 self loop
    dinv[i] = rsqrtf((float)deg);
    fillpos[i] = r0;
  }
}

__global__ void k_fill(const int* __restrict__ ei, const float* __restrict__ dinv,
                       int* __restrict__ fillpos, int2* __restrict__ epair) {
  int e = blockIdx.x * blockDim.x + threadIdx.x;
  if (e < NE) {
    int s = ei[e];
    int d = ei[NE + e];
    int pos = atomicAdd(&fillpos[d], 1);
    float c = dinv[s] * dinv[d];
    epair[pos] = make_int2(s, __float_as_int(c));
  }
}

// ---------------- GEMM: C[M,N] = A[M,128] * B[128,N], bf16 out ----------------

template <typename TA, int N, int BM>
__global__ __launch_bounds__(256) void k_gemm(const TA* __restrict__ A,
                                              const float* __restrict__ B,
                                              bf16* __restrict__ C) {
  constexpr int K = 128;
  constexpr int KC = 16;
  constexpr int NG = N / 8;
  __shared__ float Alds[BM][K + 1];
  __shared__ float Blds[KC][N];
  const int tid = threadIdx.x;
  const int row0 = blockIdx.x * BM;

  for (int idx = tid; idx < BM * K; idx += 256) {
    int r = idx >> 7;
    int k = idx & 127;
    int gr = row0 + r;
    Alds[r][k] = (gr < NN) ? toF(A[(size_t)gr * K + k]) : 0.f;
  }

  const int tn = tid % NG;
  const int tm = tid / NG;
  float acc[4][8];
#pragma unroll
  for (int i = 0; i < 4; ++i)
#pragma unroll
    for (int j = 0; j < 8; ++j) acc[i][j] = 0.f;

  for (int k0 = 0; k0 < K; k0 += KC) {
    __syncthreads();
    for (int idx = tid; idx < KC * N; idx += 256) {
      int kk = idx / N;
      int c = idx % N;
      Blds[kk][c] = B[(size_t)(k0 + kk) * N + c];
    }
    __syncthreads();
#pragma unroll
    for (int kk = 0; kk < KC; ++kk) {
      float aa[4];
#pragma unroll
      for (int i = 0; i < 4; ++i) aa[i] = Alds[tm * 4 + i][k0 + kk];
      const float4 b0 = *(const float4*)&Blds[kk][tn * 8];
      const float4 b1 = *(const float4*)&Blds[kk][tn * 8 + 4];
      const float bb[8] = {b0.x, b0.y, b0.z, b0.w, b1.x, b1.y, b1.z, b1.w};
#pragma unroll
      for (int i = 0; i < 4; ++i)
#pragma unroll
        for (int j = 0; j < 8; ++j) acc[i][j] = fmaf(aa[i], bb[j], acc[i][j]);
    }
  }

#pragma unroll
  for (int i = 0; i < 4; ++i) {
    int gr = row0 + tm * 4 + i;
    if (gr < NN) {
#pragma unroll
      for (int j = 0; j < 8; ++j)
        C[(size_t)gr * N + tn * 8 + j] = __float2bfloat16(acc[i][j]);
    }
  }
}

// ---------------- aggregation: out[n] = sum_in-edges coef*xw[src] + dinv(n)^2*xw[n] + b ----------------

template <int F, bool RELU>
__global__ __launch_bounds__(F / 2) void k_agg(const bf16* __restrict__ xw,
                                               const float* __restrict__ bias,
                                               const int* __restrict__ rowptr,
                                               const int2* __restrict__ epair,
                                               const float* __restrict__ dinv,
                                               bf16* __restrict__ out) {
  const int n = blockIdx.x;
  const int t = threadIdx.x;  // F/2 threads, 2 features each
  const bf162* __restrict__ xw2 = (const bf162*)xw;
  bf162* __restrict__ out2 = (bf162*)out;

  float dn = dinv[n];
  bf162 sv = xw2[(size_t)n * (F / 2) + t];
  float accx = __bfloat162float(sv.x) * dn * dn;
  float accy = __bfloat162float(sv.y) * dn * dn;

  int r0 = rowptr[n];
  int r1 = rowptr[n + 1];
  for (int i = r0; i < r1; ++i) {
    int2 p = epair[i];
    int s = p.x;
    float c = __int_as_float(p.y);
    bf162 m = xw2[(size_t)s * (F / 2) + t];
    accx = fmaf(c, __bfloat162float(m.x), accx);
    accy = fmaf(c, __bfloat162float(m.y), accy);
  }
  accx += bias[2 * t];
  accy += bias[2 * t + 1];
  if (RELU) {
    accx = fmaxf(accx, 0.f);
    accy = fmaxf(accy, 0.f);
  }
  bf162 o;
  o.x = __float2bfloat16(accx);
  o.y = __float2bfloat16(accy);
  out2[(size_t)n * (F / 2) + t] = o;
}

// ---------------- mean pool over sorted batch ----------------

__global__ void k_pool(const bf16* __restrict__ h2, const int* __restrict__ batch,
                       float* __restrict__ pooled) {
  int g = blockIdx.x;
  int t = threadIdx.x;  // 256
  int lo = 0, hi = NN;
  while (lo < hi) {
    int mid = (lo + hi) >> 1;
    if (batch[mid] < g) lo = mid + 1; else hi = mid;
  }
  int start = lo;
  hi = NN;
  while (lo < hi) {
    int mid = (lo + hi) >> 1;
    if (batch[mid] < g + 1) lo = mid + 1; else hi = mid;
  }
  int end = lo;
  float s = 0.f;
  for (int n = start; n < end; ++n) s += __bfloat162float(h2[(size_t)n * H2F + t]);
  float c = (float)(end - start);
  pooled[g * H2F + t] = s / fmaxf(c, 1.f);
}

// ---------------- heads ----------------

__global__ void k_heads(const float* __restrict__ pooled, const float* __restrict__ Wg,
                        const float* __restrict__ bg, const float* __restrict__ Wf,
                        const float* __restrict__ bfb, float* __restrict__ out) {
  int b = blockIdx.x;
  int t = threadIdx.x;  // 256
  __shared__ float p[H2F];
  p[t] = pooled[b * H2F + t];
  __syncthreads();
  if (t < NGRP) {
    float acc = bg[t];
    for (int d = 0; d < H2F; ++d) acc = fmaf(p[d], Wg[d * NGRP + t], acc);
    out[b * NGRP + t] = acc;
  } else if (t >= 64 && t < 64 + NGRP * NFAM) {
    int u = t - 64;
    int g = u / NFAM;
    int f = u % NFAM;
    float acc = bfb[g * NFAM + f];
    for (int d = 0; d < H2F; ++d) acc = fmaf(p[d], Wf[(g * H2F + d) * NFAM + f], acc);
    out[NGR * NGRP + (size_t)g * NGR * NFAM + b * NFAM + f] = acc;
  }
}

// ---------------- launch ----------------

extern "C" void kernel_launch(void* const* d_in, const int* in_sizes, int n_in,
                              void* d_out, int out_size, void* d_ws, size_t ws_size,
                              hipStream_t stream) {
  const float* x    = (const float*)d_in[0];
  const int*   ei   = (const int*)d_in[1];
  const int*   batch= (const int*)d_in[2];
  const float* W1   = (const float*)d_in[3];
  const float* b1   = (const float*)d_in[4];
  const float* W2   = (const float*)d_in[5];
  const float* b2   = (const float*)d_in[6];
  const float* Wg   = (const float*)d_in[7];
  const float* bg   = (const float*)d_in[8];
  const float* Wf   = (const float*)d_in[9];
  const float* bfb  = (const float*)d_in[10];
  float* out = (float*)d_out;

  char* w = (char*)d_ws;
  auto take = [&](size_t bytes) {
    char* p = w;
    w += (bytes + 255) & ~(size_t)255;
    return (void*)p;
  };
  int*   cnt     = (int*)take((size_t)NN * 4);
  int*   rowptr  = (int*)take((size_t)(NN + 1) * 4);
  int*   fillpos = (int*)take((size_t)NN * 4);
  int*   bsum    = (int*)take((size_t)SCAN_NB * 4);
  int*   boff    = (int*)take((size_t)SCAN_NB * 4);
  float* dinv    = (float*)take((size_t)NN * 4);
  int2*  epair   = (int2*)take((size_t)NE * 8);
  bf16*  xw1     = (bf16*)take((size_t)NN * KF * 2);
  bf16*  h1      = (bf16*)take((size_t)NN * KF * 2);
  bf16*  xw2     = (bf16*)take((size_t)NN * H2F * 2);
  bf16*  h2      = (bf16*)take((size_t)NN * H2F * 2);
  float* pooled  = (float*)take((size_t)NGR * H2F * 4);

  hipMemsetAsync(cnt, 0, (size_t)NN * sizeof(int), stream);
  k_hist<<<(NE + 255) / 256, 256, 0, stream>>>(ei, cnt);
  k_scan1<<<SCAN_NB, 256, 0, stream>>>(cnt, bsum);
  k_scan2<<<1, 64, 0, stream>>>(bsum, boff);
  k_scan3<<<SCAN_NB, 256, 0, stream>>>(cnt, boff, rowptr);
  k_dinv<<<(NN + 255) / 256, 256, 0, stream>>>(rowptr, dinv, fillpos);
  k_fill<<<(NE + 255) / 256, 256, 0, stream>>>(ei, dinv, fillpos, epair);

  k_gemm<float, KF, 64><<<(NN + 63) / 64, 256, 0, stream>>>(x, W1, xw1);
  k_agg<KF, true><<<NN, KF / 2, 0, stream>>>(xw1, b1, rowptr, epair, dinv, h1);
  k_gemm<bf16, H2F, 32><<<(NN + 31) / 32, 256, 0, stream>>>(h1, W2, xw2);
  k_agg<H2F, false><<<NN, H2F / 2, 0, stream>>>(xw2, b2, rowptr, epair, dinv, h2);

  k_pool<<<NGR, H2F, 0, stream>>>(h2, batch, pooled);
  k_heads<<<NGR, 256, 0, stream>>>(pooled, Wg, bg, Wf, bfb, out);
}

// Round 2
// 589.020 us; speedup vs baseline: 1.5006x; 1.5006x over previous
//
#include <hip/hip_runtime.h>
#include <hip/hip_bf16.h>

#define NN 100000     // nodes
#define NE 1600000    // edges
#define NGR 512       // graphs
#define KF 128        // IN_F == H1 == K of both GEMMs
#define H2F 256
#define NGRP 16
#define NFAM 10

#define SCAN_CHUNK 1024
#define SCAN_NB ((NN + SCAN_CHUNK - 1) / SCAN_CHUNK)

typedef __hip_bfloat16 bf16;
typedef __attribute__((ext_vector_type(8))) short short8;
typedef __attribute__((ext_vector_type(4))) float floatx4;

// bf16 helpers without struct types (keeps everything in plain ints/floats)
__device__ __forceinline__ unsigned short f2bf(float f) {
  unsigned u = __float_as_uint(f);
  unsigned r = (u + 0x7fff + ((u >> 16) & 1)) >> 16;
  return (unsigned short)r;
}
__device__ __forceinline__ float2 bf2f(unsigned u) {
  float2 r;
  r.x = __uint_as_float(u << 16);
  r.y = __uint_as_float(u & 0xffff0000u);
  return r;
}

// ---------------- CSR build ----------------

__global__ void k_hist(const int* __restrict__ ei, int* __restrict__ cnt) {
  int e = blockIdx.x * blockDim.x + threadIdx.x;
  if (e < NE) atomicAdd(&cnt[ei[NE + e]], 1);
}

__global__ void k_scan1(const int* __restrict__ cnt, int* __restrict__ bsum) {
  __shared__ int sh[256];
  int base = blockIdx.x * SCAN_CHUNK;
  int t = threadIdx.x;
  int s = 0;
  for (int i = t; i < SCAN_CHUNK; i += 256) {
    int idx = base + i;
    s += (idx < NN) ? cnt[idx] : 0;
  }
  sh[t] = s;
  __syncthreads();
  for (int off = 128; off > 0; off >>= 1) {
    if (t < off) sh[t] += sh[t + off];
    __syncthreads();
  }
  if (t == 0) bsum[blockIdx.x] = sh[0];
}

__global__ void k_scan2(const int* __restrict__ bsum, int* __restrict__ boff) {
  __shared__ int sh[128];
  int t = threadIdx.x;
  int v = (t < SCAN_NB) ? bsum[t] : 0;
  sh[t] = v;
  __syncthreads();
  for (int off = 1; off < 128; off <<= 1) {
    int val = (t >= off) ? sh[t - off] : 0;
    __syncthreads();
    sh[t] += val;
    __syncthreads();
  }
  if (t < SCAN_NB) boff[t] = sh[t] - v;  // exclusive
}

__global__ void k_scan3(const int* __restrict__ cnt, const int* __restrict__ boff,
                        int* __restrict__ rowptr) {
  __shared__ int sh[256];
  int base = blockIdx.x * SCAN_CHUNK;
  int t = threadIdx.x;
  int i0 = base + t * 4;
  int v[4];
  int loc = 0;
#pragma unroll
  for (int j = 0; j < 4; ++j) {
    int idx = i0 + j;
    v[j] = (idx < NN) ? cnt[idx] : 0;
    loc += v[j];
  }
  sh[t] = loc;
  __syncthreads();
  for (int off = 1; off < 256; off <<= 1) {
    int val = (t >= off) ? sh[t - off] : 0;
    __syncthreads();
    sh[t] += val;
    __syncthreads();
  }
  int excl = sh[t] - loc + boff[blockIdx.x];
#pragma unroll
  for (int j = 0; j < 4; ++j) {
    int idx = i0 + j;
    if (idx < NN) rowptr[idx] = excl;
    excl += v[j];
  }
  if (blockIdx.x == 0 && t == 0) rowptr[NN] = NE;
}

__global__ void k_dinv(const int* __restrict__ rowptr, float* __restrict__ dinv,
                       int* __restrict__ fillpos) {
  int i = blockIdx.x * blockDim.x + threadIdx.x;
  if (i < NN) {
    int r0 = rowptr[i];
    int deg = rowptr[i + 1] - r0 + 1;  // +1 self loop
    dinv[i] = rsqrtf((float)deg);
    fillpos[i] = r0;
  }
}

__global__ void k_fill(const int* __restrict__ ei, const float* __restrict__ dinv,
                       int* __restrict__ fillpos, int2* __restrict__ epair) {
  int e = blockIdx.x * blockDim.x + threadIdx.x;
  if (e < NE) {
    int s = ei[e];
    int d = ei[NE + e];
    int pos = atomicAdd(&fillpos[d], 1);
    float c = dinv[s] * dinv[d];
    epair[pos] = make_int2(s, __float_as_int(c));
  }
}

// ---------------- B pre-swizzle into MFMA B-operand fragment layout ----------------
// Bp[((kc*NCH + nc)*64 + lane)*8 + j] = bf16(W[(kc*32 + (lane>>4)*8 + j)*Ncol + nc*16 + (lane&15)])

__global__ void k_prepB(const float* __restrict__ W, unsigned short* __restrict__ Bp,
                        int Ncol) {
  int idx = blockIdx.x * 256 + threadIdx.x;
  int total = 128 * Ncol;
  if (idx >= total) return;
  int NCH = Ncol >> 4;
  int j = idx & 7;
  int l = (idx >> 3) & 63;
  int rest = idx >> 9;
  int nc = rest % NCH;
  int kc = rest / NCH;
  int k = kc * 32 + (l >> 4) * 8 + j;
  int nn = nc * 16 + (l & 15);
  Bp[idx] = f2bf(W[k * Ncol + nn]);
}

// ---------------- MFMA GEMM: C[M,N] = A[M,128] @ B[128,N], bf16 out ----------------
// one wave per 16 rows; A frag: lane holds A[row0 + (lane&15)][kc*32 + (lane>>4)*8 + j]
// C/D layout: col = lane&15, row = (lane>>4)*4 + reg

template <typename TA, int N>
__global__ __launch_bounds__(256) void k_gemm_mfma(const TA* __restrict__ A,
                                                   const unsigned short* __restrict__ Bp,
                                                   unsigned short* __restrict__ C) {
  constexpr int K = 128;
  constexpr int NCH = N / 16;
  const int wv = blockIdx.x * 4 + (threadIdx.x >> 6);
  const int row0 = wv * 16;
  if (row0 >= NN) return;  // 100000 % 16 == 0, so valid waves need no row guards
  const int lane = threadIdx.x & 63;
  const int m = lane & 15;
  const int q = lane >> 4;

  floatx4 acc[NCH];
#pragma unroll
  for (int i = 0; i < NCH; ++i) acc[i] = (floatx4){0.f, 0.f, 0.f, 0.f};

  const int arow = row0 + m;
#pragma unroll
  for (int kc = 0; kc < 4; ++kc) {
    short8 af;
    if constexpr (sizeof(TA) == 4) {
      const float* ap = (const float*)A + (size_t)arow * K + kc * 32 + q * 8;
      float4 f0 = *(const float4*)ap;
      float4 f1 = *(const float4*)(ap + 4);
      af[0] = (short)f2bf(f0.x); af[1] = (short)f2bf(f0.y);
      af[2] = (short)f2bf(f0.z); af[3] = (short)f2bf(f0.w);
      af[4] = (short)f2bf(f1.x); af[5] = (short)f2bf(f1.y);
      af[6] = (short)f2bf(f1.z); af[7] = (short)f2bf(f1.w);
    } else {
      af = *(const short8*)((const unsigned short*)A + (size_t)arow * K + kc * 32 + q * 8);
    }
    const unsigned short* bp = Bp + (size_t)kc * NCH * 512;
#pragma unroll
    for (int nc = 0; nc < NCH; ++nc) {
      short8 bfr = *(const short8*)(bp + (size_t)nc * 512 + lane * 8);
      acc[nc] = __builtin_amdgcn_mfma_f32_16x16x32_bf16(af, bfr, acc[nc], 0, 0, 0);
    }
  }

#pragma unroll
  for (int nc = 0; nc < NCH; ++nc) {
#pragma unroll
    for (int r = 0; r < 4; ++r) {
      int row = row0 + q * 4 + r;
      C[(size_t)row * N + nc * 16 + m] = f2bf(acc[nc][r]);
    }
  }
}

// ---------------- aggregation: one wave per node, 4-edge unrolled gathers ----------------

template <int F, bool RELU>
__global__ __launch_bounds__(128) void k_agg(const unsigned short* __restrict__ xw,
                                             const float* __restrict__ bias,
                                             const int* __restrict__ rowptr,
                                             const int2* __restrict__ epair,
                                             const float* __restrict__ dinv,
                                             unsigned short* __restrict__ out) {
  constexpr int V = F / 64;  // bf16 per lane: 2 (F=128) or 4 (F=256)
  const int n = blockIdx.x * 2 + (threadIdx.x >> 6);
  const int t = threadIdx.x & 63;

  float acc[V];
  float dn = dinv[n];
  float dn2 = dn * dn;

  if constexpr (V == 2) {
    unsigned u = ((const unsigned*)xw)[(size_t)n * 64 + t];
    float2 f = bf2f(u);
    acc[0] = f.x * dn2; acc[1] = f.y * dn2;
  } else {
    uint2 u = ((const uint2*)xw)[(size_t)n * 64 + t];
    float2 f0 = bf2f(u.x), f1 = bf2f(u.y);
    acc[0] = f0.x * dn2; acc[1] = f0.y * dn2;
    acc[2] = f1.x * dn2; acc[3] = f1.y * dn2;
  }

  const int r0 = rowptr[n];
  const int r1 = rowptr[n + 1];
  int i = r0;
  for (; i + 4 <= r1; i += 4) {
    int2 p0 = epair[i], p1 = epair[i + 1], p2 = epair[i + 2], p3 = epair[i + 3];
    float c0 = __int_as_float(p0.y), c1 = __int_as_float(p1.y);
    float c2 = __int_as_float(p2.y), c3 = __int_as_float(p3.y);
    if constexpr (V == 2) {
      const unsigned* p = (const unsigned*)xw;
      unsigned u0 = p[(size_t)p0.x * 64 + t];
      unsigned u1 = p[(size_t)p1.x * 64 + t];
      unsigned u2 = p[(size_t)p2.x * 64 + t];
      unsigned u3 = p[(size_t)p3.x * 64 + t];
      float2 f;
      f = bf2f(u0); acc[0] = fmaf(c0, f.x, acc[0]); acc[1] = fmaf(c0, f.y, acc[1]);
      f = bf2f(u1); acc[0] = fmaf(c1, f.x, acc[0]); acc[1] = fmaf(c1, f.y, acc[1]);
      f = bf2f(u2); acc[0] = fmaf(c2, f.x, acc[0]); acc[1] = fmaf(c2, f.y, acc[1]);
      f = bf2f(u3); acc[0] = fmaf(c3, f.x, acc[0]); acc[1] = fmaf(c3, f.y, acc[1]);
    } else {
      const uint2* p = (const uint2*)xw;
      uint2 w0 = p[(size_t)p0.x * 64 + t];
      uint2 w1 = p[(size_t)p1.x * 64 + t];
      uint2 w2 = p[(size_t)p2.x * 64 + t];
      uint2 w3 = p[(size_t)p3.x * 64 + t];
      float2 fa, fb;
      fa = bf2f(w0.x); fb = bf2f(w0.y);
      acc[0] = fmaf(c0, fa.x, acc[0]); acc[1] = fmaf(c0, fa.y, acc[1]);
      acc[2] = fmaf(c0, fb.x, acc[2]); acc[3] = fmaf(c0, fb.y, acc[3]);
      fa = bf2f(w1.x); fb = bf2f(w1.y);
      acc[0] = fmaf(c1, fa.x, acc[0]); acc[1] = fmaf(c1, fa.y, acc[1]);
      acc[2] = fmaf(c1, fb.x, acc[2]); acc[3] = fmaf(c1, fb.y, acc[3]);
      fa = bf2f(w2.x); fb = bf2f(w2.y);
      acc[0] = fmaf(c2, fa.x, acc[0]); acc[1] = fmaf(c2, fa.y, acc[1]);
      acc[2] = fmaf(c2, fb.x, acc[2]); acc[3] = fmaf(c2, fb.y, acc[3]);
      fa = bf2f(w3.x); fb = bf2f(w3.y);
      acc[0] = fmaf(c3, fa.x, acc[0]); acc[1] = fmaf(c3, fa.y, acc[1]);
      acc[2] = fmaf(c3, fb.x, acc[2]); acc[3] = fmaf(c3, fb.y, acc[3]);
    }
  }
  for (; i < r1; ++i) {
    int2 pe = epair[i];
    float c = __int_as_float(pe.y);
    if constexpr (V == 2) {
      unsigned u = ((const unsigned*)xw)[(size_t)pe.x * 64 + t];
      float2 f = bf2f(u);
      acc[0] = fmaf(c, f.x, acc[0]); acc[1] = fmaf(c, f.y, acc[1]);
    } else {
      uint2 u = ((const uint2*)xw)[(size_t)pe.x * 64 + t];
      float2 f0 = bf2f(u.x), f1 = bf2f(u.y);
      acc[0] = fmaf(c, f0.x, acc[0]); acc[1] = fmaf(c, f0.y, acc[1]);
      acc[2] = fmaf(c, f1.x, acc[2]); acc[3] = fmaf(c, f1.y, acc[3]);
    }
  }

  if constexpr (V == 2) {
    float2 bb = ((const float2*)bias)[t];
    acc[0] += bb.x; acc[1] += bb.y;
    if (RELU) { acc[0] = fmaxf(acc[0], 0.f); acc[1] = fmaxf(acc[1], 0.f); }
    unsigned o = (unsigned)f2bf(acc[0]) | ((unsigned)f2bf(acc[1]) << 16);
    ((unsigned*)out)[(size_t)n * 64 + t] = o;
  } else {
    float4 bb = ((const float4*)bias)[t];
    acc[0] += bb.x; acc[1] += bb.y; acc[2] += bb.z; acc[3] += bb.w;
    if (RELU) {
      acc[0] = fmaxf(acc[0], 0.f); acc[1] = fmaxf(acc[1], 0.f);
      acc[2] = fmaxf(acc[2], 0.f); acc[3] = fmaxf(acc[3], 0.f);
    }
    uint2 o;
    o.x = (unsigned)f2bf(acc[0]) | ((unsigned)f2bf(acc[1]) << 16);
    o.y = (unsigned)f2bf(acc[2]) | ((unsigned)f2bf(acc[3]) << 16);
    ((uint2*)out)[(size_t)n * 64 + t] = o;
  }
}

// ---------------- mean pool over sorted batch ----------------

__global__ void k_pool(const unsigned short* __restrict__ h2, const int* __restrict__ batch,
                       float* __restrict__ pooled) {
  int g = blockIdx.x;
  int t = threadIdx.x;  // 256
  int lo = 0, hi = NN;
  while (lo < hi) {
    int mid = (lo + hi) >> 1;
    if (batch[mid] < g) lo = mid + 1; else hi = mid;
  }
  int start = lo;
  hi = NN;
  while (lo < hi) {
    int mid = (lo + hi) >> 1;
    if (batch[mid] < g + 1) lo = mid + 1; else hi = mid;
  }
  int end = lo;
  float s = 0.f;
  for (int n = start; n < end; ++n)
    s += __uint_as_float((unsigned)h2[(size_t)n * H2F + t] << 16);
  float c = (float)(end - start);
  pooled[g * H2F + t] = s / fmaxf(c, 1.f);
}

// ---------------- heads ----------------

__global__ void k_heads(const float* __restrict__ pooled, const float* __restrict__ Wg,
                        const float* __restrict__ bg, const float* __restrict__ Wf,
                        const float* __restrict__ bfb, float* __restrict__ out) {
  int b = blockIdx.x;
  int t = threadIdx.x;  // 256
  __shared__ float p[H2F];
  p[t] = pooled[b * H2F + t];
  __syncthreads();
  if (t < NGRP) {
    float acc = bg[t];
    for (int d = 0; d < H2F; ++d) acc = fmaf(p[d], Wg[d * NGRP + t], acc);
    out[b * NGRP + t] = acc;
  } else if (t >= 64 && t < 64 + NGRP * NFAM) {
    int u = t - 64;
    int g = u / NFAM;
    int f = u % NFAM;
    float acc = bfb[g * NFAM + f];
    for (int d = 0; d < H2F; ++d) acc = fmaf(p[d], Wf[(g * H2F + d) * NFAM + f], acc);
    out[NGR * NGRP + (size_t)g * NGR * NFAM + b * NFAM + f] = acc;
  }
}

// ---------------- launch ----------------

extern "C" void kernel_launch(void* const* d_in, const int* in_sizes, int n_in,
                              void* d_out, int out_size, void* d_ws, size_t ws_size,
                              hipStream_t stream) {
  const float* x    = (const float*)d_in[0];
  const int*   ei   = (const int*)d_in[1];
  const int*   batch= (const int*)d_in[2];
  const float* W1   = (const float*)d_in[3];
  const float* b1   = (const float*)d_in[4];
  const float* W2   = (const float*)d_in[5];
  const float* b2   = (const float*)d_in[6];
  const float* Wg   = (const float*)d_in[7];
  const float* bg   = (const float*)d_in[8];
  const float* Wf   = (const float*)d_in[9];
  const float* bfb  = (const float*)d_in[10];
  float* out = (float*)d_out;

  char* w = (char*)d_ws;
  auto take = [&](size_t bytes) {
    char* p = w;
    w += (bytes + 255) & ~(size_t)255;
    return (void*)p;
  };
  int*   cnt     = (int*)take((size_t)NN * 4);
  int*   rowptr  = (int*)take((size_t)(NN + 1) * 4);
  int*   fillpos = (int*)take((size_t)NN * 4);
  int*   bsum    = (int*)take((size_t)SCAN_NB * 4);
  int*   boff    = (int*)take((size_t)SCAN_NB * 4);
  float* dinv    = (float*)take((size_t)NN * 4);
  int2*  epair   = (int2*)take((size_t)NE * 8);
  unsigned short* Bp1 = (unsigned short*)take((size_t)KF * KF * 2);
  unsigned short* Bp2 = (unsigned short*)take((size_t)KF * H2F * 2);
  unsigned short* xw1 = (unsigned short*)take((size_t)NN * KF * 2);
  unsigned short* h1  = (unsigned short*)take((size_t)NN * KF * 2);
  unsigned short* xw2 = (unsigned short*)take((size_t)NN * H2F * 2);
  unsigned short* h2  = (unsigned short*)take((size_t)NN * H2F * 2);
  float* pooled  = (float*)take((size_t)NGR * H2F * 4);

  hipMemsetAsync(cnt, 0, (size_t)NN * sizeof(int), stream);
  k_hist<<<(NE + 255) / 256, 256, 0, stream>>>(ei, cnt);
  k_scan1<<<SCAN_NB, 256, 0, stream>>>(cnt, bsum);
  k_scan2<<<1, 128, 0, stream>>>(bsum, boff);
  k_scan3<<<SCAN_NB, 256, 0, stream>>>(cnt, boff, rowptr);
  k_dinv<<<(NN + 255) / 256, 256, 0, stream>>>(rowptr, dinv, fillpos);
  k_fill<<<(NE + 255) / 256, 256, 0, stream>>>(ei, dinv, fillpos, epair);

  k_prepB<<<(KF * KF + 255) / 256, 256, 0, stream>>>(W1, Bp1, KF);
  k_prepB<<<(KF * H2F + 255) / 256, 256, 0, stream>>>(W2, Bp2, H2F);

  // waves = ceil(100000/16) = 6250 -> 1563 blocks x 4 waves (extras guarded)
  k_gemm_mfma<float, KF><<<1563, 256, 0, stream>>>(x, Bp1, xw1);
  k_agg<KF, true><<<NN / 2, 128, 0, stream>>>(xw1, b1, rowptr, epair, dinv, h1);
  k_gemm_mfma<unsigned short, H2F><<<1563, 256, 0, stream>>>(h1, Bp2, xw2);
  k_agg<H2F, false><<<NN / 2, 128, 0, stream>>>(xw2, b2, rowptr, epair, dinv, h2);

  k_pool<<<NGR, H2F, 0, stream>>>(h2, batch, pooled);
  k_heads<<<NGR, 256, 0, stream>>>(pooled, Wg, bg, Wf, bfb, out);
}

// Round 3
// 439.716 us; speedup vs baseline: 2.0101x; 1.3395x over previous
//
#include <hip/hip_runtime.h>
#include <hip/hip_bf16.h>

#define NN 100000     // nodes
#define NE 1600000    // edges
#define NGR 512       // graphs
#define KF 128        // IN_F == H1
#define H2F 256
#define NGRP 16
#define NFAM 10

#define SCAN_CHUNK 1024
#define SCAN_NB ((NN + SCAN_CHUNK - 1) / SCAN_CHUNK)

typedef __attribute__((ext_vector_type(8))) short short8;
typedef __attribute__((ext_vector_type(4))) float floatx4;

__device__ __forceinline__ unsigned short f2bf(float f) {
  unsigned u = __float_as_uint(f);
  unsigned r = (u + 0x7fff + ((u >> 16) & 1)) >> 16;
  return (unsigned short)r;
}
__device__ __forceinline__ float2 bf2f(unsigned u) {
  float2 r;
  r.x = __uint_as_float(u << 16);
  r.y = __uint_as_float(u & 0xffff0000u);
  return r;
}

// ---------------- CSR build ----------------

__global__ void k_hist(const int* __restrict__ ei, int* __restrict__ cnt) {
  int e = blockIdx.x * blockDim.x + threadIdx.x;
  if (e < NE) atomicAdd(&cnt[ei[NE + e]], 1);
}

__global__ void k_scan1(const int* __restrict__ cnt, int* __restrict__ bsum) {
  __shared__ int sh[256];
  int base = blockIdx.x * SCAN_CHUNK;
  int t = threadIdx.x;
  int s = 0;
  for (int i = t; i < SCAN_CHUNK; i += 256) {
    int idx = base + i;
    s += (idx < NN) ? cnt[idx] : 0;
  }
  sh[t] = s;
  __syncthreads();
  for (int off = 128; off > 0; off >>= 1) {
    if (t < off) sh[t] += sh[t + off];
    __syncthreads();
  }
  if (t == 0) bsum[blockIdx.x] = sh[0];
}

__global__ void k_scan2(const int* __restrict__ bsum, int* __restrict__ boff) {
  __shared__ int sh[128];
  int t = threadIdx.x;
  int v = (t < SCAN_NB) ? bsum[t] : 0;
  sh[t] = v;
  __syncthreads();
  for (int off = 1; off < 128; off <<= 1) {
    int val = (t >= off) ? sh[t - off] : 0;
    __syncthreads();
    sh[t] += val;
    __syncthreads();
  }
  if (t < SCAN_NB) boff[t] = sh[t] - v;  // exclusive
}

__global__ void k_scan3(const int* __restrict__ cnt, const int* __restrict__ boff,
                        int* __restrict__ rowptr) {
  __shared__ int sh[256];
  int base = blockIdx.x * SCAN_CHUNK;
  int t = threadIdx.x;
  int i0 = base + t * 4;
  int v[4];
  int loc = 0;
#pragma unroll
  for (int j = 0; j < 4; ++j) {
    int idx = i0 + j;
    v[j] = (idx < NN) ? cnt[idx] : 0;
    loc += v[j];
  }
  sh[t] = loc;
  __syncthreads();
  for (int off = 1; off < 256; off <<= 1) {
    int val = (t >= off) ? sh[t - off] : 0;
    __syncthreads();
    sh[t] += val;
    __syncthreads();
  }
  int excl = sh[t] - loc + boff[blockIdx.x];
#pragma unroll
  for (int j = 0; j < 4; ++j) {
    int idx = i0 + j;
    if (idx < NN) rowptr[idx] = excl;
    excl += v[j];
  }
  if (blockIdx.x == 0 && t == 0) rowptr[NN] = NE;
}

__global__ void k_dinv(const int* __restrict__ rowptr, float* __restrict__ dinv,
                       int* __restrict__ fillpos) {
  int i = blockIdx.x * blockDim.x + threadIdx.x;
  if (i < NN) {
    int r0 = rowptr[i];
    int deg = rowptr[i + 1] - r0 + 1;  // +1 self loop
    dinv[i] = rsqrtf((float)deg);
    fillpos[i] = r0;
  }
}

__global__ void k_fill(const int* __restrict__ ei, const float* __restrict__ dinv,
                       int* __restrict__ fillpos, int2* __restrict__ epair) {
  int e = blockIdx.x * blockDim.x + threadIdx.x;
  if (e < NE) {
    int s = ei[e];
    int d = ei[NE + e];
    int pos = atomicAdd(&fillpos[d], 1);
    float c = dinv[s] * dinv[d];
    epair[pos] = make_int2(s, __float_as_int(c));
  }
}

// ---------------- B pre-swizzle (W1 only) into MFMA B-fragment layout ----------------

__global__ void k_prepB(const float* __restrict__ W, unsigned short* __restrict__ Bp,
                        int Ncol) {
  int idx = blockIdx.x * 256 + threadIdx.x;
  int total = 128 * Ncol;
  if (idx >= total) return;
  int NCH = Ncol >> 4;
  int j = idx & 7;
  int l = (idx >> 3) & 63;
  int rest = idx >> 9;
  int nc = rest % NCH;
  int kc = rest / NCH;
  int k = kc * 32 + (l >> 4) * 8 + j;
  int nn = nc * 16 + (l & 15);
  Bp[idx] = f2bf(W[k * Ncol + nn]);
}

// ---------------- MFMA GEMM1: C[M,128] = A[M,128] @ B[128,128], bf16 out ----------------

__global__ __launch_bounds__(256) void k_gemm_mfma(const float* __restrict__ A,
                                                   const unsigned short* __restrict__ Bp,
                                                   unsigned short* __restrict__ C) {
  constexpr int K = 128;
  constexpr int N = KF;
  constexpr int NCH = N / 16;
  const int wv = blockIdx.x * 4 + (threadIdx.x >> 6);
  const int row0 = wv * 16;
  if (row0 >= NN) return;  // 100000 % 16 == 0
  const int lane = threadIdx.x & 63;
  const int m = lane & 15;
  const int q = lane >> 4;

  floatx4 acc[NCH];
#pragma unroll
  for (int i = 0; i < NCH; ++i) acc[i] = (floatx4){0.f, 0.f, 0.f, 0.f};

  const int arow = row0 + m;
#pragma unroll
  for (int kc = 0; kc < 4; ++kc) {
    const float* ap = A + (size_t)arow * K + kc * 32 + q * 8;
    float4 f0 = *(const float4*)ap;
    float4 f1 = *(const float4*)(ap + 4);
    short8 af;
    af[0] = (short)f2bf(f0.x); af[1] = (short)f2bf(f0.y);
    af[2] = (short)f2bf(f0.z); af[3] = (short)f2bf(f0.w);
    af[4] = (short)f2bf(f1.x); af[5] = (short)f2bf(f1.y);
    af[6] = (short)f2bf(f1.z); af[7] = (short)f2bf(f1.w);
    const unsigned short* bp = Bp + (size_t)kc * NCH * 512;
#pragma unroll
    for (int nc = 0; nc < NCH; ++nc) {
      short8 bfr = *(const short8*)(bp + (size_t)nc * 512 + lane * 8);
      acc[nc] = __builtin_amdgcn_mfma_f32_16x16x32_bf16(af, bfr, acc[nc], 0, 0, 0);
    }
  }

#pragma unroll
  for (int nc = 0; nc < NCH; ++nc) {
#pragma unroll
    for (int r = 0; r < 4; ++r) {
      int row = row0 + q * 4 + r;
      C[(size_t)row * N + nc * 16 + m] = f2bf(acc[nc][r]);
    }
  }
}

// ---------------- aggregation, F=128: one wave per node, 8-edge unrolled ----------------
// out[n] = sum_in coef*xw[src] + dinv(n)^2*xw[n]  (+bias) (relu)

template <bool RELU, bool BIAS>
__global__ __launch_bounds__(128) void k_agg(const unsigned short* __restrict__ xw,
                                             const float* __restrict__ bias,
                                             const int* __restrict__ rowptr,
                                             const int2* __restrict__ epair,
                                             const float* __restrict__ dinv,
                                             unsigned short* __restrict__ out) {
  const int n = blockIdx.x * 2 + (threadIdx.x >> 6);
  const int t = threadIdx.x & 63;
  const unsigned* __restrict__ p = (const unsigned*)xw;  // 64 uints per row

  float dn = dinv[n];
  float dn2 = dn * dn;
  float2 f = bf2f(p[(size_t)n * 64 + t]);
  float ax = f.x * dn2, ay = f.y * dn2;

  const int r0 = rowptr[n];
  const int r1 = rowptr[n + 1];
  int i = r0;
  for (; i + 8 <= r1; i += 8) {
    int2 e0 = epair[i], e1 = epair[i + 1], e2 = epair[i + 2], e3 = epair[i + 3];
    int2 e4 = epair[i + 4], e5 = epair[i + 5], e6 = epair[i + 6], e7 = epair[i + 7];
    unsigned u0 = p[(size_t)e0.x * 64 + t];
    unsigned u1 = p[(size_t)e1.x * 64 + t];
    unsigned u2 = p[(size_t)e2.x * 64 + t];
    unsigned u3 = p[(size_t)e3.x * 64 + t];
    unsigned u4 = p[(size_t)e4.x * 64 + t];
    unsigned u5 = p[(size_t)e5.x * 64 + t];
    unsigned u6 = p[(size_t)e6.x * 64 + t];
    unsigned u7 = p[(size_t)e7.x * 64 + t];
    f = bf2f(u0); ax = fmaf(__int_as_float(e0.y), f.x, ax); ay = fmaf(__int_as_float(e0.y), f.y, ay);
    f = bf2f(u1); ax = fmaf(__int_as_float(e1.y), f.x, ax); ay = fmaf(__int_as_float(e1.y), f.y, ay);
    f = bf2f(u2); ax = fmaf(__int_as_float(e2.y), f.x, ax); ay = fmaf(__int_as_float(e2.y), f.y, ay);
    f = bf2f(u3); ax = fmaf(__int_as_float(e3.y), f.x, ax); ay = fmaf(__int_as_float(e3.y), f.y, ay);
    f = bf2f(u4); ax = fmaf(__int_as_float(e4.y), f.x, ax); ay = fmaf(__int_as_float(e4.y), f.y, ay);
    f = bf2f(u5); ax = fmaf(__int_as_float(e5.y), f.x, ax); ay = fmaf(__int_as_float(e5.y), f.y, ay);
    f = bf2f(u6); ax = fmaf(__int_as_float(e6.y), f.x, ax); ay = fmaf(__int_as_float(e6.y), f.y, ay);
    f = bf2f(u7); ax = fmaf(__int_as_float(e7.y), f.x, ax); ay = fmaf(__int_as_float(e7.y), f.y, ay);
  }
  for (; i + 4 <= r1; i += 4) {
    int2 e0 = epair[i], e1 = epair[i + 1], e2 = epair[i + 2], e3 = epair[i + 3];
    unsigned u0 = p[(size_t)e0.x * 64 + t];
    unsigned u1 = p[(size_t)e1.x * 64 + t];
    unsigned u2 = p[(size_t)e2.x * 64 + t];
    unsigned u3 = p[(size_t)e3.x * 64 + t];
    f = bf2f(u0); ax = fmaf(__int_as_float(e0.y), f.x, ax); ay = fmaf(__int_as_float(e0.y), f.y, ay);
    f = bf2f(u1); ax = fmaf(__int_as_float(e1.y), f.x, ax); ay = fmaf(__int_as_float(e1.y), f.y, ay);
    f = bf2f(u2); ax = fmaf(__int_as_float(e2.y), f.x, ax); ay = fmaf(__int_as_float(e2.y), f.y, ay);
    f = bf2f(u3); ax = fmaf(__int_as_float(e3.y), f.x, ax); ay = fmaf(__int_as_float(e3.y), f.y, ay);
  }
  for (; i < r1; ++i) {
    int2 e = epair[i];
    float c = __int_as_float(e.y);
    f = bf2f(p[(size_t)e.x * 64 + t]);
    ax = fmaf(c, f.x, ax); ay = fmaf(c, f.y, ay);
  }

  if (BIAS) {
    float2 bb = ((const float2*)bias)[t];
    ax += bb.x; ay += bb.y;
  }
  if (RELU) { ax = fmaxf(ax, 0.f); ay = fmaxf(ay, 0.f); }
  ((unsigned*)out)[(size_t)n * 64 + t] =
      (unsigned)f2bf(ax) | ((unsigned)f2bf(ay) << 16);
}

// ---------------- mean pool over sorted batch (F=128, bf16 in, f32 out) ----------------

__global__ __launch_bounds__(256) void k_pool(const unsigned short* __restrict__ h,
                                              const int* __restrict__ batch,
                                              float* __restrict__ pooled_raw) {
  int g = blockIdx.x;
  int t = threadIdx.x & 63;   // feature uint (2 bf16)
  int wv = threadIdx.x >> 6;  // 4 waves split the node range
  int lo = 0, hi = NN;
  while (lo < hi) { int mid = (lo + hi) >> 1; if (batch[mid] < g) lo = mid + 1; else hi = mid; }
  int start = lo;
  hi = NN;
  while (lo < hi) { int mid = (lo + hi) >> 1; if (batch[mid] < g + 1) lo = mid + 1; else hi = mid; }
  int end = lo;

  const unsigned* __restrict__ p = (const unsigned*)h;
  float sx = 0.f, sy = 0.f;
  int n = start + wv;
  for (; n + 12 < end; n += 16) {  // 4-deep unroll per wave (stride 4 waves)
    unsigned u0 = p[(size_t)n * 64 + t];
    unsigned u1 = p[(size_t)(n + 4) * 64 + t];
    unsigned u2 = p[(size_t)(n + 8) * 64 + t];
    unsigned u3 = p[(size_t)(n + 12) * 64 + t];
    float2 f0 = bf2f(u0), f1 = bf2f(u1), f2 = bf2f(u2), f3 = bf2f(u3);
    sx += (f0.x + f1.x) + (f2.x + f3.x);
    sy += (f0.y + f1.y) + (f2.y + f3.y);
  }
  for (; n < end; n += 4) {
    float2 f = bf2f(p[(size_t)n * 64 + t]);
    sx += f.x; sy += f.y;
  }

  __shared__ float sh[4][128];
  sh[wv][2 * t] = sx;
  sh[wv][2 * t + 1] = sy;
  __syncthreads();
  if (wv == 0) {
    float vx = sh[0][2 * t] + sh[1][2 * t] + sh[2][2 * t] + sh[3][2 * t];
    float vy = sh[0][2 * t + 1] + sh[1][2 * t + 1] + sh[2][2 * t + 1] + sh[3][2 * t + 1];
    float c = fmaxf((float)(end - start), 1.f);
    pooled_raw[g * KF + 2 * t] = vx / c;
    pooled_raw[g * KF + 2 * t + 1] = vy / c;
  }
}

// ---------------- fused mini-GEMM (pooled = praw @ W2 + b2) + heads ----------------

__global__ __launch_bounds__(256) void k_heads(const float* __restrict__ praw,
                                               const float* __restrict__ W2,
                                               const float* __restrict__ b2,
                                               const float* __restrict__ Wg,
                                               const float* __restrict__ bg,
                                               const float* __restrict__ Wf,
                                               const float* __restrict__ bfb,
                                               float* __restrict__ out) {
  int b = blockIdx.x;
  int t = threadIdx.x;  // 256
  __shared__ float pr[KF];
  __shared__ float p[H2F];
  if (t < KF) pr[t] = praw[b * KF + t];
  __syncthreads();
  float acc = b2[t];
#pragma unroll 8
  for (int d = 0; d < KF; ++d) acc = fmaf(pr[d], W2[d * H2F + t], acc);
  p[t] = acc;
  __syncthreads();
  if (t < NGRP) {
    float a = bg[t];
    for (int d = 0; d < H2F; ++d) a = fmaf(p[d], Wg[d * NGRP + t], a);
    out[b * NGRP + t] = a;
  } else if (t >= 64 && t < 64 + NGRP * NFAM) {
    int u = t - 64;
    int g = u / NFAM;
    int ff = u % NFAM;
    float a = bfb[g * NFAM + ff];
    for (int d = 0; d < H2F; ++d) a = fmaf(p[d], Wf[(g * H2F + d) * NFAM + ff], a);
    out[NGR * NGRP + (size_t)g * NGR * NFAM + b * NFAM + ff] = a;
  }
}

// ---------------- launch ----------------

extern "C" void kernel_launch(void* const* d_in, const int* in_sizes, int n_in,
                              void* d_out, int out_size, void* d_ws, size_t ws_size,
                              hipStream_t stream) {
  const float* x    = (const float*)d_in[0];
  const int*   ei   = (const int*)d_in[1];
  const int*   batch= (const int*)d_in[2];
  const float* W1   = (const float*)d_in[3];
  const float* b1   = (const float*)d_in[4];
  const float* W2   = (const float*)d_in[5];
  const float* b2   = (const float*)d_in[6];
  const float* Wg   = (const float*)d_in[7];
  const float* bg   = (const float*)d_in[8];
  const float* Wf   = (const float*)d_in[9];
  const float* bfb  = (const float*)d_in[10];
  float* out = (float*)d_out;

  char* w = (char*)d_ws;
  auto take = [&](size_t bytes) {
    char* p = w;
    w += (bytes + 255) & ~(size_t)255;
    return (void*)p;
  };
  int*   cnt     = (int*)take((size_t)NN * 4);
  int*   rowptr  = (int*)take((size_t)(NN + 1) * 4);
  int*   fillpos = (int*)take((size_t)NN * 4);
  int*   bsum    = (int*)take((size_t)SCAN_NB * 4);
  int*   boff    = (int*)take((size_t)SCAN_NB * 4);
  float* dinv    = (float*)take((size_t)NN * 4);
  int2*  epair   = (int2*)take((size_t)NE * 8);
  unsigned short* Bp1  = (unsigned short*)take((size_t)KF * KF * 2);
  unsigned short* xw1  = (unsigned short*)take((size_t)NN * KF * 2);
  unsigned short* h1   = (unsigned short*)take((size_t)NN * KF * 2);
  unsigned short* agg2 = (unsigned short*)take((size_t)NN * KF * 2);
  float* praw    = (float*)take((size_t)NGR * KF * 4);

  hipMemsetAsync(cnt, 0, (size_t)NN * sizeof(int), stream);
  k_hist<<<(NE + 255) / 256, 256, 0, stream>>>(ei, cnt);
  k_scan1<<<SCAN_NB, 256, 0, stream>>>(cnt, bsum);
  k_scan2<<<1, 128, 0, stream>>>(bsum, boff);
  k_scan3<<<SCAN_NB, 256, 0, stream>>>(cnt, boff, rowptr);
  k_dinv<<<(NN + 255) / 256, 256, 0, stream>>>(rowptr, dinv, fillpos);
  k_fill<<<(NE + 255) / 256, 256, 0, stream>>>(ei, dinv, fillpos, epair);

  k_prepB<<<(KF * KF + 255) / 256, 256, 0, stream>>>(W1, Bp1, KF);
  k_gemm_mfma<<<1563, 256, 0, stream>>>(x, Bp1, xw1);

  k_agg<true, true><<<NN / 2, 128, 0, stream>>>(xw1, b1, rowptr, epair, dinv, h1);
  k_agg<false, false><<<NN / 2, 128, 0, stream>>>(h1, nullptr, rowptr, epair, dinv, agg2);

  k_pool<<<NGR, 256, 0, stream>>>(agg2, batch, praw);
  k_heads<<<NGR, 256, 0, stream>>>(praw, W2, b2, Wg, bg, Wf, bfb, out);
}